// Round 9
// baseline (204.005 us; speedup 1.0000x reference)
//
#include <hip/hip_runtime.h>
#include <stdint.h>

#define B_ 4
#define S_ 2048
#define D_ 1024
#define H_ 16
#define DH_ 64
#define M_TOT (B_*S_)   // 8192
#define N1_ (3*D_)      // 3072
#define K_ D_           // 1024
#define NCH 8           // s-chunks for attention score partials

typedef __bf16 bf16_8 __attribute__((ext_vector_type(8)));
typedef float  f32x4  __attribute__((ext_vector_type(4)));
typedef unsigned short u16;

typedef __attribute__((address_space(1))) const void* gas_t;
typedef __attribute__((address_space(3))) void*       las_t;

__device__ __forceinline__ unsigned short f2bf(float f) {
    union { float f; unsigned u; } v; v.f = f;
    unsigned r = v.u + 0x7FFFu + ((v.u >> 16) & 1u);
    return (unsigned short)(r >> 16);
}

__device__ __forceinline__ void async_ld16(const void* g, void* l) {
    __builtin_amdgcn_global_load_lds((gas_t)g, (las_t)l, 16, 0, 0);
}

// ---------------- cast fp32 -> bf16 (X, W1, W2) ----------------
__global__ __launch_bounds__(256)
void cast_kernel(const float* __restrict__ X, const float* __restrict__ W1,
                 const float* __restrict__ W2, unsigned short* __restrict__ Xb,
                 unsigned short* __restrict__ W1b, unsigned short* __restrict__ W2b) {
    const int nX  = (M_TOT * K_) / 4;   // 2097152
    const int nW1 = (N1_ * K_) / 4;     // 786432
    int i = blockIdx.x * 256 + threadIdx.x;   // float4 index
    const float4* src; unsigned short* dst; int j;
    if (i < nX)            { src = (const float4*)X;  dst = Xb;  j = i; }
    else if (i < nX + nW1) { src = (const float4*)W1; dst = W1b; j = i - nX; }
    else                   { src = (const float4*)W2; dst = W2b; j = i - nX - nW1; }
    float4 v = src[j];
    ushort4 o;
    o.x = f2bf(v.x); o.y = f2bf(v.y); o.z = f2bf(v.z); o.w = f2bf(v.w);
    ((ushort4*)dst)[j] = o;
}

// ---------------- gemm_bt: C[M,N] = A[M,K] * B[N,K]^T + bias ----------------
// Round-0 proven structure: 128x128 tile, 4 waves (2x2), BK=64,
// global_load_lds width 16, XOR-swizzled LDS (0 bank conflicts), XCD swizzle.
// EPI: 0 = fp32 C[M,N]   (GEMM2)
//      2 = QKV split: Q,K TRANSPOSED to QT/KT[B,H,64,S] (coalesced ushort4
//          along s); V to per-head Vh[B,H,S,64] (rows of 64 e, 128B store
//          stride -> PV kernel's V slice is one contiguous 32KB region).
template<int N, int NBX, int EPI>
__global__ __launch_bounds__(256)
void gemm_bt(const unsigned short* __restrict__ A,
             const unsigned short* __restrict__ Bm,
             const float* __restrict__ bias,
             void* __restrict__ C, int K,
             u16* __restrict__ QT, u16* __restrict__ KT, u16* __restrict__ Vh) {
    __shared__ unsigned short As[128 * 64];
    __shared__ unsigned short Bs[128 * 64];
    const int t    = threadIdx.x;
    const int wid  = t >> 6;
    const int lane = t & 63;
    const int lrow = lane & 15;
    const int lq   = lane >> 4;

    const int lid  = blockIdx.y * NBX + blockIdx.x;
    const int xcd  = lid & 7;
    const int slot = lid >> 3;
    const int by   = xcd * (gridDim.y >> 3) + slot / NBX;
    const int bx   = slot % NBX;
    const int m0   = by * 128;
    const int n0   = bx * 128;

    const int wm   = (wid >> 1) * 64;
    const int wn   = (wid & 1) * 64;

    f32x4 acc[4][4] = {};

    for (int k0 = 0; k0 < K; k0 += 64) {
#pragma unroll
        for (int p = 0; p < 4; p++) {
            const int c   = p * 256 + t;          // chunk 0..1023
            const int row = c >> 3;
            const int kb  = (c & 7) ^ (row & 7);  // un-swizzled global k-block
            async_ld16(A  + (size_t)(m0 + row) * K + k0 + kb * 8, (char*)As + c * 16);
            async_ld16(Bm + (size_t)(n0 + row) * K + k0 + kb * 8, (char*)Bs + c * 16);
        }
        __syncthreads();

#pragma unroll
        for (int ks = 0; ks < 2; ks++) {
            bf16_8 af[4], bfr[4];
#pragma unroll
            for (int mt = 0; mt < 4; mt++) {
                const int r  = wm + mt * 16 + lrow;
                const int kb = (ks * 4 + lq) ^ (r & 7);
                af[mt] = *(const bf16_8*)(As + (r * 8 + kb) * 8);
            }
#pragma unroll
            for (int nt = 0; nt < 4; nt++) {
                const int r  = wn + nt * 16 + lrow;
                const int kb = (ks * 4 + lq) ^ (r & 7);
                bfr[nt] = *(const bf16_8*)(Bs + (r * 8 + kb) * 8);
            }
#pragma unroll
            for (int mt = 0; mt < 4; mt++)
#pragma unroll
                for (int nt = 0; nt < 4; nt++)
                    acc[mt][nt] = __builtin_amdgcn_mfma_f32_16x16x32_bf16(af[mt], bfr[nt], acc[mt][nt], 0, 0, 0);
        }
        __syncthreads();
    }

    // epilogue: C row = m0+wm+mt*16+lq*4+i, col = n0+wn+nt*16+lrow
#pragma unroll
    for (int nt = 0; nt < 4; nt++) {
        const int col = n0 + wn + nt * 16 + lrow;
        const float bv = bias[col];
#pragma unroll
        for (int mt = 0; mt < 4; mt++) {
            const int row = m0 + wm + mt * 16 + lq * 4;
            f32x4 a = acc[mt][nt];
            if constexpr (EPI == 2) {
                ushort4 o;
                o.x = f2bf(a[0] + bv); o.y = f2bf(a[1] + bv);
                o.z = f2bf(a[2] + bv); o.w = f2bf(a[3] + bv);
                const int b = row >> 11, s = row & 2047;
                const int d = col & 63;
                if (col < 1024) {
                    *(ushort4*)(QT + ((size_t)(b * 16 + (col >> 6)) * 64 + d) * (size_t)S_ + s) = o;
                } else if (col < 2048) {
                    *(ushort4*)(KT + ((size_t)(b * 16 + ((col >> 6) - 16)) * 64 + d) * (size_t)S_ + s) = o;
                } else {
                    const int h = (col >> 6) - 32, e = col & 63;
                    u16* vp = Vh + ((size_t)(b * 16 + h) * S_ + s) * 64 + e;
                    vp[0]   = o.x;           // rows s..s+3, 128B apart;
                    vp[64]  = o.y;           // lanes 0-15 cover 16 consecutive e
                    vp[128] = o.z;           // -> 32B contiguous segments
                    vp[192] = o.w;
                }
            } else {
                float* Cp = (float*)C;
#pragma unroll
                for (int i = 0; i < 4; i++)
                    Cp[(size_t)(row + i) * N + col] = a[i] + bv;
            }
        }
    }
}

// ---------------- attn_qk: per-head scores via staged batched GEMM -----------
// grid (bh=64, ch=8), 256 thr / 4 waves (2x2 over 32x32 of the 64x64 tile).
// partial[d][e] = sum_{s in chunk} QT[d][s]*KT[e][s]. Q/K staged coalesced via
// global_load_lds -> each element read once chip-wide. (Round-8: part of the
// 213.8 -> 200.0 win.)
__global__ __launch_bounds__(256)
void attn_qk(const u16* __restrict__ QT, const u16* __restrict__ KT,
             float* __restrict__ Scp) {
    __shared__ u16 Qs[64 * 64];
    __shared__ u16 Ks[64 * 64];
    const int bh = blockIdx.x, ch = blockIdx.y;
    const int t = threadIdx.x, wid = t >> 6, lane = t & 63;
    const int lrow = lane & 15, lq = lane >> 4;
    const int wm2 = (wid >> 1) * 32, wn2 = (wid & 1) * 32;
    const u16* Qh = QT + (size_t)bh * 64 * S_;
    const u16* Kh = KT + (size_t)bh * 64 * S_;

    f32x4 acc[2][2] = {};
    for (int kt = 0; kt < 4; kt++) {
        const int s0 = ch * 256 + kt * 64;
#pragma unroll
        for (int p = 0; p < 4; p++) {
            const int c   = p * 256 + t;          // 0..1023: 0..511 Q, 512..1023 K
            const int cc  = c & 511;
            const int row = cc >> 3;
            const int kb  = (cc & 7) ^ (row & 7);
            if (p < 2)
                async_ld16(Qh + (size_t)row * S_ + s0 + kb * 8, (char*)Qs + cc * 16);
            else
                async_ld16(Kh + (size_t)row * S_ + s0 + kb * 8, (char*)Ks + cc * 16);
        }
        __syncthreads();
#pragma unroll
        for (int ks = 0; ks < 2; ks++) {
            bf16_8 aq[2], bk[2];
#pragma unroll
            for (int mt = 0; mt < 2; mt++) {
                const int r  = wm2 + mt * 16 + lrow;
                const int kb = (ks * 4 + lq) ^ (r & 7);
                aq[mt] = *(const bf16_8*)(Qs + (r * 8 + kb) * 8);
            }
#pragma unroll
            for (int nt = 0; nt < 2; nt++) {
                const int r  = wn2 + nt * 16 + lrow;
                const int kb = (ks * 4 + lq) ^ (r & 7);
                bk[nt] = *(const bf16_8*)(Ks + (r * 8 + kb) * 8);
            }
#pragma unroll
            for (int mt = 0; mt < 2; mt++)
#pragma unroll
                for (int nt = 0; nt < 2; nt++)
                    acc[mt][nt] = __builtin_amdgcn_mfma_f32_16x16x32_bf16(aq[mt], bk[nt], acc[mt][nt], 0, 0, 0);
        }
        __syncthreads();
    }

    float* out = Scp + (size_t)(bh * NCH + ch) * 4096;
#pragma unroll
    for (int mt = 0; mt < 2; mt++)
#pragma unroll
        for (int nt = 0; nt < 2; nt++)
#pragma unroll
            for (int i = 0; i < 4; i++)
                out[(wm2 + mt * 16 + lq * 4 + i) * 64 + wn2 + nt * 16 + lrow] = acc[mt][nt][i];
}

// ---------------- attn_softmax: reduce partials + softmax (verified) ---------
// Restored as a separate kernel: reducing Scp ONCE here (8MB read) replaces
// the fused kernel's 8x-redundant 64MB of Scp reads.
__global__ __launch_bounds__(256)
void attn_softmax(const float* __restrict__ Scp, unsigned short* __restrict__ Wb) {
    const int bh = blockIdx.x;
    const int t = threadIdx.x;
    const int d = t >> 2, q = t & 3;
    float s[16] = {};
#pragma unroll
    for (int c = 0; c < NCH; c++) {
        const float4* p = (const float4*)(Scp + ((size_t)(bh * NCH + c) * 64 + d) * 64 + q * 16);
#pragma unroll
        for (int j = 0; j < 4; j++) {
            float4 v = p[j];
            s[j*4+0] += v.x; s[j*4+1] += v.y; s[j*4+2] += v.z; s[j*4+3] += v.w;
        }
    }
    const float scale = 0.022097086912079608f;  // 1/sqrt(2048)
    float m = -3.0e38f;
#pragma unroll
    for (int i = 0; i < 16; i++) { s[i] *= scale; m = fmaxf(m, s[i]); }
    m = fmaxf(m, __shfl_xor(m, 1));
    m = fmaxf(m, __shfl_xor(m, 2));
    float sum = 0.f;
#pragma unroll
    for (int i = 0; i < 16; i++) { s[i] = __expf(s[i] - m); sum += s[i]; }
    sum += __shfl_xor(sum, 1);
    sum += __shfl_xor(sum, 2);
    const float inv = 1.0f / sum;
    unsigned short* w = Wb + (size_t)bh * 4096 + d * 64 + q * 16;
    ushort4 o0, o1, o2, o3;
    o0.x=f2bf(s[0]*inv);  o0.y=f2bf(s[1]*inv);  o0.z=f2bf(s[2]*inv);  o0.w=f2bf(s[3]*inv);
    o1.x=f2bf(s[4]*inv);  o1.y=f2bf(s[5]*inv);  o1.z=f2bf(s[6]*inv);  o1.w=f2bf(s[7]*inv);
    o2.x=f2bf(s[8]*inv);  o2.y=f2bf(s[9]*inv);  o2.z=f2bf(s[10]*inv); o2.w=f2bf(s[11]*inv);
    o3.x=f2bf(s[12]*inv); o3.y=f2bf(s[13]*inv); o3.z=f2bf(s[14]*inv); o3.w=f2bf(s[15]*inv);
    ((ushort4*)w)[0]=o0; ((ushort4*)w)[1]=o1; ((ushort4*)w)[2]=o2; ((ushort4*)w)[3]=o3;
}

// ---------------- attn_pv: O = w @ V^T, fully staged ------------------------
// grid (bh=64, sc=8), 256 thr / 4 waves. Single-shot K=64 GEMM:
// stage Ws (8KB, w head) + Vs (32KB, Vh slice rows sc*256..+255 — one
// CONTIGUOUS region) via global_load_lds + XOR swizzle; one MFMA pass
// (32 MFMA/wave); write O[b,h,d,s]. LDS 40KB -> 4 blocks/CU.
__global__ __launch_bounds__(256)
void attn_pv(const u16* __restrict__ Wb, const u16* __restrict__ Vh,
             u16* __restrict__ O) {
    __shared__ u16 Ws[64 * 64];
    __shared__ u16 Vs[256 * 64];
    const int bh = blockIdx.x, sc = blockIdx.y;
    const int t = threadIdx.x, wid = t >> 6, lane = t & 63;
    const int lrow = lane & 15, lq = lane >> 4;
    const u16* Wh = Wb + (size_t)bh * 4096;
    const u16* Vp = Vh + ((size_t)bh * S_ + sc * 256) * 64;

#pragma unroll
    for (int j = 0; j < 2; j++) {
        const int c = j * 256 + t;                  // 512 chunks of w
        const int row = c >> 3, kb = (c & 7) ^ (row & 7);
        async_ld16(Wh + row * 64 + kb * 8, (char*)Ws + c * 16);
    }
#pragma unroll
    for (int p = 0; p < 8; p++) {
        const int c = p * 256 + t;                  // 2048 chunks of V slice
        const int row = c >> 3, kb = (c & 7) ^ (row & 7);
        async_ld16(Vp + (size_t)row * 64 + kb * 8, (char*)Vs + c * 16);
    }
    __syncthreads();

    f32x4 acc[4][4] = {};
#pragma unroll
    for (int ks = 0; ks < 2; ks++) {
        bf16_8 af[4], bfr[4];
#pragma unroll
        for (int mt = 0; mt < 4; mt++) {
            const int r  = mt * 16 + lrow;
            const int kb = (ks * 4 + lq) ^ (r & 7);
            af[mt] = *(const bf16_8*)(Ws + (r * 8 + kb) * 8);
        }
#pragma unroll
        for (int nt = 0; nt < 4; nt++) {
            const int r  = wid * 64 + nt * 16 + lrow;
            const int kb = (ks * 4 + lq) ^ (r & 7);
            bfr[nt] = *(const bf16_8*)(Vs + (r * 8 + kb) * 8);
        }
#pragma unroll
        for (int mt = 0; mt < 4; mt++)
#pragma unroll
            for (int nt = 0; nt < 4; nt++)
                acc[mt][nt] = __builtin_amdgcn_mfma_f32_16x16x32_bf16(af[mt], bfr[nt], acc[mt][nt], 0, 0, 0);
    }

    const size_t obase = (size_t)bh * (DH_ * S_);
    const int s0 = sc * 256 + wid * 64;
#pragma unroll
    for (int mt = 0; mt < 4; mt++)
#pragma unroll
        for (int nt = 0; nt < 4; nt++) {
            const int d = mt * 16 + lq * 4;
            const int s = s0 + nt * 16 + lrow;
#pragma unroll
            for (int i = 0; i < 4; i++)
                O[obase + (size_t)(d + i) * S_ + s] = f2bf(acc[mt][nt][i]);
        }
}

extern "C" void kernel_launch(void* const* d_in, const int* in_sizes, int n_in,
                              void* d_out, int out_size, void* d_ws, size_t ws_size,
                              hipStream_t stream) {
    const float* X  = (const float*)d_in[0];
    const float* W1 = (const float*)d_in[1];
    const float* b1 = (const float*)d_in[2];
    const float* W2 = (const float*)d_in[3];
    const float* b2 = (const float*)d_in[4];

    char* ws = (char*)d_ws;
    unsigned short* Xb  = (unsigned short*)(ws + 0);                 // 16 MB, dead after GEMM1
    unsigned short* W1b = (unsigned short*)(ws + (16u << 20));       // 6 MB, dead after GEMM1
    unsigned short* W2b = (unsigned short*)(ws + (22u << 20));       // 2 MB
    unsigned short* QT  = (unsigned short*)(ws + (24u << 20));       // 16 MB  Q^T [B,H,64,S]
    unsigned short* KT  = (unsigned short*)(ws + (40u << 20));       // 16 MB  K^T [B,H,64,S]
    unsigned short* Vh  = (unsigned short*)(ws + (56u << 20));       // 16 MB  V [B,H,S,64]
    // after GEMM1, [0,22MB) is free:
    unsigned short* Wb  = (unsigned short*)(ws + 0);                 // 512 KB softmaxed w
    unsigned short* Ob  = (unsigned short*)(ws + (1u << 20));        // 16 MB attention output
    // d_out (32 MB fp32) is dead until GEMM2 -> use 8 MB of it for score partials
    float* Scp = (float*)d_out;

    cast_kernel<<<12288, 256, 0, stream>>>(X, W1, W2, Xb, W1b, W2b);
    gemm_bt<N1_, N1_/128, 2><<<dim3(N1_ / 128, M_TOT / 128), 256, 0, stream>>>(
        Xb, W1b, b1, nullptr, K_, QT, KT, Vh);
    attn_qk<<<dim3(64, NCH), 256, 0, stream>>>(QT, KT, Scp);
    attn_softmax<<<64, 256, 0, stream>>>(Scp, Wb);
    attn_pv<<<dim3(64, NCH), 256, 0, stream>>>(Wb, Vh, Ob);
    gemm_bt<D_, D_/128, 0><<<dim3(D_ / 128, M_TOT / 128), 256, 0, stream>>>(
        Ob, W2b, b2, d_out, K_, nullptr, nullptr, nullptr);
}